// Round 12
// baseline (12218.840 us; speedup 1.0000x reference)
//
#include <hip/hip_runtime.h>
#include <hip/hip_fp16.h>
#include <stdint.h>

#define S_LEN 512
#define HD 1280
#define GD 5120   // 4*C
#define VOC 32000

typedef __attribute__((ext_vector_type(8))) short short8;
typedef __attribute__((ext_vector_type(8))) _Float16 half8;
typedef __attribute__((ext_vector_type(4))) float floatx4;
typedef __attribute__((ext_vector_type(2))) _Float16 halfx2;
typedef __attribute__((ext_vector_type(4))) _Float16 halfx4;

#define GLB1 const __attribute__((address_space(1))) void*
#define LDS3 __attribute__((address_space(3))) void*

static __device__ __forceinline__ unsigned short f2h(float f) {
  return __builtin_bit_cast(unsigned short, (_Float16)f);
}
static __device__ __forceinline__ float h2f(unsigned short h) {
  return (float)__builtin_bit_cast(_Float16, h);
}
static __device__ __forceinline__ float tanhf_fast(float x) {
  float xc = fminf(fmaxf(x, -15.f), 15.f);
  float e = __expf(2.f * xc);
  return (e - 1.f) / (e + 1.f);
}
#if __has_builtin(__builtin_amdgcn_fdot2)
static __device__ __forceinline__ float fdot2(halfx2 a, halfx2 b, float c) {
  return __builtin_amdgcn_fdot2(a, b, c, false);
}
#else
static __device__ __forceinline__ float fdot2(halfx2 a, halfx2 b, float c) {
  return c + (float)a[0]*(float)b[0] + (float)a[1]*(float)b[1];
}
#endif
static __device__ __forceinline__ halfx2 u2h2(unsigned int u) {
  return __builtin_bit_cast(halfx2, u);
}

// ---------------------------------------------------------------------------
// Transpose + fp32->f16 convert: in (R x C) fp32 row-major -> out (C x R) f16
// ---------------------------------------------------------------------------
__global__ __launch_bounds__(256)
void transpose_cvt(const float* __restrict__ in, unsigned short* __restrict__ out,
                   int R, int C)
{
  __shared__ float tile[32][33];
  const int c0 = blockIdx.x * 32;
  const int r0 = blockIdx.y * 32;
  const int tx = threadIdx.x & 31;
  const int ty = threadIdx.x >> 5;   // 0..7
#pragma unroll
  for (int p = 0; p < 4; p++) {
    int rl = ty + p * 8;
    tile[rl][tx] = in[(size_t)(r0 + rl) * C + c0 + tx];
  }
  __syncthreads();
#pragma unroll
  for (int p = 0; p < 4; p++) {
    int cl = ty + p * 8;
    out[(size_t)(c0 + cl) * R + r0 + tx] = f2h(tile[tx][cl]);
  }
}

// ---------------------------------------------------------------------------
// Generic MFMA GEMM (fp16 inputs, fp32 accum) — unchanged from round 11.
// CMODE: 0 = xp, 1 = transposed f16 out, 2 = Hcat (+resid, rev), 3 = logits
// ---------------------------------------------------------------------------
template<int AFP32, int CMODE>
__global__ __launch_bounds__(256, 2)
void gemm_k(const void* __restrict__ Ap, const unsigned short* __restrict__ BTp,
            void* __restrict__ Cp, const float* __restrict__ bias,
            const unsigned short* __restrict__ resid,
            int M, int N, int K, int rev)
{
  __shared__ __align__(16) short As[128 * 32];
  __shared__ __align__(16) short Bs[128 * 32];
  const int tid  = threadIdx.x;
  const int row0 = blockIdx.y * 128;
  const int col0 = blockIdx.x * 128;
  const int lane = tid & 63;
  const int wid  = tid >> 6;
  const int wrow = (wid >> 1) * 64;
  const int wcol = (wid & 1) * 64;
  const int lr   = lane & 15;
  const int gg   = lane >> 4;

  floatx4 acc[4][4];
#pragma unroll
  for (int m = 0; m < 4; m++)
#pragma unroll
    for (int n = 0; n < 4; n++)
      acc[m][n] = (floatx4)0.0f;

  for (int k0 = 0; k0 < K; k0 += 32) {
    __syncthreads();
#pragma unroll
    for (int p = 0; p < 2; p++) {
      int idx = p * 256 + tid;
      int r = idx >> 2, c = idx & 3;
      if constexpr (AFP32) {
        const float* src = (const float*)Ap + (size_t)(row0 + r) * K + k0 + c * 8;
        floatx4 f0 = *(const floatx4*)src;
        floatx4 f1 = *(const floatx4*)(src + 4);
        short8 va;
        va[0] = (short)f2h(f0[0]); va[1] = (short)f2h(f0[1]);
        va[2] = (short)f2h(f0[2]); va[3] = (short)f2h(f0[3]);
        va[4] = (short)f2h(f1[0]); va[5] = (short)f2h(f1[1]);
        va[6] = (short)f2h(f1[2]); va[7] = (short)f2h(f1[3]);
        *(short8*)&As[r * 32 + ((c ^ (r & 3)) * 8)] = va;
      } else {
        const unsigned short* gsa =
          (const unsigned short*)Ap + (size_t)(row0 + r) * K + k0 + ((c ^ (r & 3)) * 8);
        __builtin_amdgcn_global_load_lds((GLB1)gsa, (LDS3)&As[idx * 8], 16, 0, 0);
      }
      const unsigned short* gsb =
        BTp + (size_t)(col0 + r) * K + k0 + ((c ^ (r & 3)) * 8);
      __builtin_amdgcn_global_load_lds((GLB1)gsb, (LDS3)&Bs[idx * 8], 16, 0, 0);
    }
    __syncthreads();   // drains vmcnt(0): async LDS fills complete
    short8 af[4], bfv[4];
#pragma unroll
    for (int m = 0; m < 4; m++) {
      int r = wrow + m * 16 + lr;
      af[m] = *(const short8*)&As[r * 32 + ((gg ^ (r & 3)) * 8)];
    }
#pragma unroll
    for (int n = 0; n < 4; n++) {
      int c = wcol + n * 16 + lr;
      bfv[n] = *(const short8*)&Bs[c * 32 + ((gg ^ (c & 3)) * 8)];
    }
#pragma unroll
    for (int m = 0; m < 4; m++)
#pragma unroll
      for (int n = 0; n < 4; n++)
        acc[m][n] = __builtin_amdgcn_mfma_f32_16x16x32_f16(
            __builtin_bit_cast(half8, af[m]), __builtin_bit_cast(half8, bfv[n]),
            acc[m][n], 0, 0, 0);
  }

  // Epilogue. Verified C layout: col = lane&15, row = 4*(lane>>4) + i.
#pragma unroll
  for (int m = 0; m < 4; m++) {
    int rbase = row0 + wrow + m * 16 + 4 * gg;
#pragma unroll
    for (int n = 0; n < 4; n++) {
      int col = col0 + wcol + n * 16 + lr;
      if constexpr (CMODE == 1) {
        halfx4 t4;
#pragma unroll
        for (int i = 0; i < 4; i++) t4[i] = (_Float16)acc[m][n][i];
        *(halfx4*)((_Float16*)Cp + (size_t)col * M + rbase) = t4;
      } else if constexpr (CMODE == 0) {
        float bv = bias[col];
#pragma unroll
        for (int i = 0; i < 4; i++) {
          int r = rbase + i;
          int b = r >> 9, s = r & 511;          // A rows are (b,s)
          int so = rev ? (511 - s) : s;
          ((float*)Cp)[(size_t)((so << 1) | b) * GD + col] = acc[m][n][i] + bv;
        }
      } else if constexpr (CMODE == 2) {
#pragma unroll
        for (int i = 0; i < 4; i++) {
          int r = rbase + i;
          int t = r >> 1, b = r & 1;            // A rows (Pout) are (t,b)
          int s = rev ? (511 - t) : t;
          size_t o = (size_t)((b << 9) | s) * HD + col;
          float v = acc[m][n][i];
          if (resid) v += h2f(resid[o]);
          ((unsigned short*)Cp)[o] = f2h(v);
        }
      } else {
        float bv = bias[col];
#pragma unroll
        for (int i = 0; i < 4; i++)
          ((float*)Cp)[(size_t)(rbase + i) * N + col] = acc[m][n][i] + bv;
      }
    }
  }
}

// ---------------------------------------------------------------------------
// FUSED two-layer persistent LSTM scan — 513 rounds (layer-1 lags by 1 step).
// gate0_t = xp0_t + p0_{t-1}@Wf0 ; gate1_t = p0_t@Wg + p1_{t-1}@Wf1 + b1
// (Wg = Wp0@Wi1, Wf = Wp@Ws, precomputed f16).
// 256 WGs (dir = bid&1, g = bid>>1, 10 h-idx each), 768 threads (12 waves):
//   team A (tid<256): layer-0 matvec, Wf0 slice in LDS (v8 structure).
//   team B (tid>=256): layer-1 double matvec, Wg+Wf1 slices REGISTER-resident
//     (btid = tid-256: wave wB=btid>>6 owns 5 cols, lane lB=btid&63 owns 20 k).
// Sync per round = v3 protocol verbatim: 32 counters/dir, RMW by tid0,
// 1-wave poll, bulk coalesced pull of BOTH payloads (p0,p1) -> LDS,
// 3 barriers. ALL publishers (p0: tid 0-9, p1: tid 10-19) are in WAVE 0, so
// tid0's s_waitcnt vmcnt(0) drains every payload store before the RMW.
// Slot invariant: publish(r)->slot (r+1)&1, consume(r)->slot r&1; a WG can't
// publish round r+1 before all WGs staged round r (poll gates it). 
// ---------------------------------------------------------------------------
__global__ __launch_bounds__(768, 3)
void lstm_scan2(const _Float16* __restrict__ wf0T,  // [2dir][GD][HD]
                const _Float16* __restrict__ wf1T,  // [2dir][GD][HD]
                const _Float16* __restrict__ wgT,   // [2dir][GD][HD]
                const float* __restrict__ xp,       // [2dir][1024][GD] layer0
                const float* __restrict__ b1f,      // [GD] layer1 fwd bias
                const float* __restrict__ b1b,      // [GD] layer1 bwd bias
                unsigned short* __restrict__ Pout0, // [2dir][1024][HD] f16
                unsigned short* __restrict__ Pout1, // [2dir][1024][HD] f16
                unsigned int* __restrict__ pbuf,    // [2dir][2slot][2lay][2b][640]
                unsigned int* __restrict__ ctr)     // [2dir][32]
{
  const int dir = blockIdx.x & 1;
  const int g   = blockIdx.x >> 1;    // 0..127
  const int jbase = g * 10;
  const int tid = threadIdx.x;

  __shared__ __align__(16) unsigned int wlds[40 * 640];   // L0 Wf slice 102400 B
  __shared__ __align__(16) unsigned int plds[2 * 1280];   // [lay][b][640]  10240 B
  __shared__ float gvals0[40][2];
  __shared__ float gvals1[40][2];

  // ---- stage layer-0 weight slice into LDS (all 768 threads) ----
  for (int i = 0; i < 9; i++) {
    int idx = i * 768 + tid;          // 16B-chunk index, 6400 total
    if (idx < 6400) {
      int c = idx / 160, r = idx - c * 160;
      size_t rowIdx = (size_t)dir * GD + (c / 10) * HD + jbase + (c % 10);
      *(uint4*)&wlds[c * 640 + r * 4] = ((const uint4*)(wf0T + rowIdx * HD))[r];
    }
  }

  // ---- team A ids (layer 0), identical to v8 ----
  const int ks = tid & 31;            // k-slice (40 f16)
  const int cg = (tid & 255) >> 5;    // col-group (5 cols)
  int gcol[5];
#pragma unroll
  for (int i = 0; i < 5; i++) {
    int c = cg * 5 + i;
    gcol[i] = (c / 10) * HD + jbase + (c % 10);
  }
  const bool isRed = (tid < 256) && (ks == 0);

  // ---- team B (layer 1): register-resident Wg/Wf1 slices ----
  const int btid = tid - 256;         // valid for tid>=256
  const int wB = btid >> 6;           // 0..7 : 5 cols each
  const int lB = btid & 63;           // 0..63: 20 f16 k-slice
  unsigned int wg_reg[5][10], wf_reg[5][10];
  if (tid >= 256) {
#pragma unroll
    for (int c = 0; c < 5; c++) {
      int cc = wB * 5 + c;
      size_t rowIdx = (size_t)dir * GD + (cc / 10) * HD + jbase + (cc % 10);
      const unsigned int* sg = (const unsigned int*)(wgT  + rowIdx * HD) + lB * 10;
      const unsigned int* sf = (const unsigned int*)(wf1T + rowIdx * HD) + lB * 10;
#pragma unroll
      for (int i = 0; i < 10; i += 2) {
        uint2 a = *(const uint2*)(sg + i); wg_reg[c][i] = a.x; wg_reg[c][i + 1] = a.y;
        uint2 b = *(const uint2*)(sf + i); wf_reg[c][i] = b.x; wf_reg[c][i + 1] = b.y;
      }
    }
  }

  // ---- owners (ALL in wave 0 so tid0's vmcnt(0) covers their stores) ----
  const bool isOwn0 = tid < 10;                    // layer-0 publish
  const int ob0 = tid & 1, op0 = tid >> 1;
  float c0a = 0.f, c0b = 0.f;
  const bool isOwn1 = (tid >= 10) && (tid < 20);   // layer-1 publish
  const int o1 = tid - 10;
  const int ob1 = o1 & 1, op1 = o1 >> 1;
  float c1a = 0.f, c1b = 0.f;
  float b1v[8];
  if (isOwn1) {
    const float* b1 = dir ? b1b : b1f;
#pragma unroll
    for (int q = 0; q < 4; q++) {
      b1v[2 * q]     = b1[q * HD + jbase + op1 * 2];
      b1v[2 * q + 1] = b1[q * HD + jbase + op1 * 2 + 1];
    }
  }

  __syncthreads();   // weights staged

  for (int r = 0; r <= S_LEN; r++) {   // 513 rounds
    // team A xp prefetch (t = r), before the poll
    float xpv[5][2];
#pragma unroll
    for (int i = 0; i < 5; i++) { xpv[i][0] = 0.f; xpv[i][1] = 0.f; }
    if (isRed && r < S_LEN) {
#pragma unroll
      for (int i = 0; i < 5; i++)
#pragma unroll
        for (int b = 0; b < 2; b++)
          xpv[i][b] = xp[((size_t)dir * 1024 + r * 2 + b) * GD + gcol[i]];
    }

    // v3 poll: wave 0 checks all 32 counters (lane&31, __all)
    if (r > 0) {
      if (tid < 64) {
        const unsigned tgt = (unsigned)r * 4u;
        const unsigned int* cp = ctr + dir * 32 + (tid & 31);
        while (true) {
          unsigned v = __hip_atomic_load(cp, __ATOMIC_RELAXED, __HIP_MEMORY_SCOPE_AGENT);
          if (__all(v >= tgt)) break;
          __builtin_amdgcn_s_sleep(1);
        }
      }
      __syncthreads();   // B1
    }

    // stage p0(r-1) + p1(r-2): 2560 u32, coalesced relaxed agent loads
    const unsigned int* prs = pbuf + (dir * 2 + (r & 1)) * 2560;
    if (tid < 512) {
#pragma unroll
      for (int i = 0; i < 5; i++)
        plds[i * 512 + tid] = __hip_atomic_load(prs + i * 512 + tid,
                                                __ATOMIC_RELAXED, __HIP_MEMORY_SCOPE_AGENT);
    }
    __syncthreads();   // B2

    if (tid < 256) {
      // ---- team A: layer-0 matvec (v8 code) ----
      float acc[5][2];
#pragma unroll
      for (int i = 0; i < 5; i++) { acc[i][0] = 0.f; acc[i][1] = 0.f; }
#pragma unroll
      for (int j = 0; j < 5; j++) {
        half8 pv0 = *(const half8*)&plds[0 * 640 + ks * 20 + j * 4];
        half8 pv1 = *(const half8*)&plds[1 * 640 + ks * 20 + j * 4];
#pragma unroll
        for (int i = 0; i < 5; i++) {
          half8 wv = *(const half8*)&wlds[(cg * 5 + i) * 640 + ks * 20 + j * 4];
#pragma unroll
          for (int u = 0; u < 4; u++) {
            halfx2 w2  = {wv[2 * u], wv[2 * u + 1]};
            halfx2 p02 = {pv0[2 * u], pv0[2 * u + 1]};
            halfx2 p12 = {pv1[2 * u], pv1[2 * u + 1]};
            acc[i][0] = fdot2(p02, w2, acc[i][0]);
            acc[i][1] = fdot2(p12, w2, acc[i][1]);
          }
        }
      }
#pragma unroll
      for (int i = 0; i < 5; i++)
#pragma unroll
        for (int b = 0; b < 2; b++) {
          float v = acc[i][b];
#pragma unroll
          for (int off = 16; off >= 1; off >>= 1)
            v += __shfl_xor(v, off, 32);
          if (isRed) gvals0[cg * 5 + i][b] = v + xpv[i][b];
        }
    } else {
      // ---- team B: layer-1 double matvec, weights in registers ----
      float acc[5][2];
#pragma unroll
      for (int c = 0; c < 5; c++) { acc[c][0] = 0.f; acc[c][1] = 0.f; }
#pragma unroll
      for (int b = 0; b < 2; b++) {
        unsigned int p0c[10], p1c[10];
#pragma unroll
        for (int i = 0; i < 10; i++) {
          p0c[i] = plds[b * 640 + lB * 10 + i];
          p1c[i] = plds[1280 + b * 640 + lB * 10 + i];
        }
#pragma unroll
        for (int c = 0; c < 5; c++) {
          float a = acc[c][b];
#pragma unroll
          for (int i = 0; i < 10; i++) {
            a = fdot2(u2h2(p0c[i]), u2h2(wg_reg[c][i]), a);
            a = fdot2(u2h2(p1c[i]), u2h2(wf_reg[c][i]), a);
          }
          acc[c][b] = a;
        }
      }
#pragma unroll
      for (int c = 0; c < 5; c++)
#pragma unroll
        for (int b = 0; b < 2; b++) {
          float v = acc[c][b];
#pragma unroll
          for (int off = 32; off >= 1; off >>= 1)
            v += __shfl_xor(v, off, 64);
          if (lB == 0) gvals1[wB * 5 + c][b] = v;
        }
    }
    __syncthreads();   // B3

    // ---- owners: cell updates + publish (wave 0 only) ----
    unsigned packed0 = 0, packed1 = 0;
    if (isOwn0 && r < S_LEN) {
      int j0 = op0 * 2, j1 = j0 + 1;
      float gi0 = gvals0[j0][ob0],      gi1 = gvals0[j1][ob0];
      float gf0 = gvals0[10 + j0][ob0], gf1 = gvals0[10 + j1][ob0];
      float gz0 = gvals0[20 + j0][ob0], gz1 = gvals0[20 + j1][ob0];
      float go0 = gvals0[30 + j0][ob0], go1 = gvals0[30 + j1][ob0];
      float si0 = 1.f / (1.f + __expf(-gi0)), si1 = 1.f / (1.f + __expf(-gi1));
      float sf0 = 1.f / (1.f + __expf(-gf0)), sf1 = 1.f / (1.f + __expf(-gf1));
      float so0 = 1.f / (1.f + __expf(-go0)), so1 = 1.f / (1.f + __expf(-go1));
      c0a = si0 * tanhf_fast(gz0) + sf0 * c0a;
      c0b = si1 * tanhf_fast(gz1) + sf1 * c0b;
      float pv0 = so0 * tanhf_fast(c0a);
      float pv1 = so1 * tanhf_fast(c0b);
      packed0 = (unsigned)f2h(pv0) | ((unsigned)f2h(pv1) << 16);
      unsigned int* pw = pbuf + (dir * 2 + ((r + 1) & 1)) * 2560
                              + 0 + ob0 * 640 + (jbase >> 1) + op0;
      __hip_atomic_store(pw, packed0, __ATOMIC_RELAXED, __HIP_MEMORY_SCOPE_AGENT);
    }
    if (isOwn1 && r >= 1) {
      int j0 = op1 * 2, j1 = j0 + 1;
      float gi0 = gvals1[j0][ob1] + b1v[0],      gi1 = gvals1[j1][ob1] + b1v[1];
      float gf0 = gvals1[10 + j0][ob1] + b1v[2], gf1 = gvals1[10 + j1][ob1] + b1v[3];
      float gz0 = gvals1[20 + j0][ob1] + b1v[4], gz1 = gvals1[20 + j1][ob1] + b1v[5];
      float go0 = gvals1[30 + j0][ob1] + b1v[6], go1 = gvals1[30 + j1][ob1] + b1v[7];
      float si0 = 1.f / (1.f + __expf(-gi0)), si1 = 1.f / (1.f + __expf(-gi1));
      float sf0 = 1.f / (1.f + __expf(-gf0)), sf1 = 1.f / (1.f + __expf(-gf1));
      float so0 = 1.f / (1.f + __expf(-go0)), so1 = 1.f / (1.f + __expf(-go1));
      c1a = si0 * tanhf_fast(gz0) + sf0 * c1a;
      c1b = si1 * tanhf_fast(gz1) + sf1 * c1b;
      float pv0 = so0 * tanhf_fast(c1a);
      float pv1 = so1 * tanhf_fast(c1b);
      packed1 = (unsigned)f2h(pv0) | ((unsigned)f2h(pv1) << 16);
      unsigned int* pw = pbuf + (dir * 2 + ((r + 1) & 1)) * 2560
                              + 1280 + ob1 * 640 + (jbase >> 1) + op1;
      __hip_atomic_store(pw, packed1, __ATOMIC_RELAXED, __HIP_MEMORY_SCOPE_AGENT);
    }
    // producer ordering: all wave-0 payload stores complete before the RMW
    asm volatile("s_waitcnt vmcnt(0)" ::: "memory");
    if (tid == 0) {
      __hip_atomic_fetch_add(ctr + dir * 32 + (g & 31), 1u,
                             __ATOMIC_RELAXED, __HIP_MEMORY_SCOPE_AGENT);
    }
    // Pout stores after the RMW: off the critical path
    if (isOwn0 && r < S_LEN)
      ((unsigned int*)Pout0)[(((size_t)dir * 1024 + r * 2 + ob0) * HD + jbase) / 2 + op0] = packed0;
    if (isOwn1 && r >= 1)
      ((unsigned int*)Pout1)[(((size_t)dir * 1024 + (r - 1) * 2 + ob1) * HD + jbase) / 2 + op1] = packed1;
  }
}

// ---------------------------------------------------------------------------
extern "C" void kernel_launch(void* const* d_in, const int* in_sizes, int n_in,
                              void* d_out, int out_size, void* d_ws, size_t ws_size,
                              hipStream_t stream)
{
  char* W = (char*)d_ws;
  // workspace (bytes). Timeline-overlapped regions:
  //  [0, 52.4M)  WS_T (Ws^T, dead after Wf GEMMs) -> WG_T (26.2M) + P1_O (5.2M)
  //  [26.2M..)   WLIN_T written AFTER projs (overlays P1_O-tail..WI_T/WP_T, all dead)
  const size_t WS_T  = 0;                    // Ws^T f16 [4][GD][HD]
  const size_t WI_T  = 52428800;             // Wi^T f16 [4][GD][HD]
  const size_t WP_T  = 104857600;            // Wp^T f16 [4][HD][HD]
  const size_t WF_T  = 117964800;            // Wf^T f16 [4][GD][HD]
  const size_t HCAT  = 170393600;            // f16 [4096][HD]
  const size_t P_O   = 180879360;            // f16 [2][1024][HD] layer0
  const size_t XP_O  = 186122240;            // f32 [2][1024][GD] layer0
  const size_t PB_O  = 228065280;            // u32 [2dir][2slot][2lay][2b][640] 40,960
  const size_t CTR_O = 228106240;            // u32 [2dir][32] 256
  const size_t NEED  = 228106496;
  const size_t WG_T  = 0;                    // Wg^T f16 [2][GD][HD] 26,214,400
  const size_t P1_O  = 27262976;             // f16 [2][1024][HD] layer1 (5.2M)
  const size_t WLIN_T= 33554432;             // f16 [VOC][HD] 81,920,000 (ends 115.5M < WF_T)
  if (ws_size < NEED) return;

  const float* x    = (const float*)d_in[0];
  const float* Wi_f = (const float*)d_in[1];
  const float* Ws_f = (const float*)d_in[2];
  const float* b_f  = (const float*)d_in[3];
  const float* Wp_f = (const float*)d_in[4];
  const float* Wi_b = (const float*)d_in[5];
  const float* Ws_b = (const float*)d_in[6];
  const float* b_b  = (const float*)d_in[7];
  const float* Wp_b = (const float*)d_in[8];
  const float* Wlin = (const float*)d_in[9];
  const float* blin = (const float*)d_in[10];

  hipMemsetAsync(W + PB_O, 0, 40960 + 256, stream);

  // Phase 1: weight transposes (+f16)
  for (int l = 0; l < 2; l++)
    for (int d = 0; d < 2; d++) {
      int ld = l * 2 + d;
      const float* ws_src = (d ? Ws_b : Ws_f) + (size_t)l * HD * GD;
      const float* wi_src = (d ? Wi_b : Wi_f) + (size_t)l * HD * GD;
      const float* wp_src = (d ? Wp_b : Wp_f) + (size_t)l * HD * HD;
      transpose_cvt<<<dim3(GD / 32, HD / 32), 256, 0, stream>>>(
        ws_src, (unsigned short*)(W + WS_T) + (size_t)ld * GD * HD, HD, GD);
      transpose_cvt<<<dim3(GD / 32, HD / 32), 256, 0, stream>>>(
        wi_src, (unsigned short*)(W + WI_T) + (size_t)ld * GD * HD, HD, GD);
      transpose_cvt<<<dim3(HD / 32, HD / 32), 256, 0, stream>>>(
        wp_src, (unsigned short*)(W + WP_T) + (size_t)ld * HD * HD, HD, HD);
    }

  // Phase 2a: Wf = Wp @ Ws (per layer,dir), transposed f16 out
  for (int l = 0; l < 2; l++)
    for (int d = 0; d < 2; d++) {
      int ld = l * 2 + d;
      const float* wp_src = (d ? Wp_b : Wp_f) + (size_t)l * HD * HD;
      gemm_k<1, 1><<<dim3(GD / 128, HD / 128), 256, 0, stream>>>(
        wp_src, (const unsigned short*)(W + WS_T) + (size_t)ld * GD * HD,
        (void*)((_Float16*)(W + WF_T) + (size_t)ld * GD * HD),
        nullptr, nullptr, HD, GD, HD, 0);
    }
  // Phase 2b: Wg = Wp0 @ Wi1 (per dir) -> WG_T (overlays dead WS_T)
  for (int d = 0; d < 2; d++) {
    const float* wp0_src = (d ? Wp_b : Wp_f);   // layer 0
    gemm_k<1, 1><<<dim3(GD / 128, HD / 128), 256, 0, stream>>>(
      wp0_src, (const unsigned short*)(W + WI_T) + (size_t)(2 + d) * GD * HD,
      (void*)((_Float16*)(W + WG_T) + (size_t)d * GD * HD),
      nullptr, nullptr, HD, GD, HD, 0);
  }

  // Phase 3: xp0 = x @ Wi0 + b0 (layer 0 only; bwd rows time-reversed)
  for (int d = 0; d < 2; d++) {
    const float* bias = (d ? b_b : b_f);        // layer 0
    gemm_k<1, 0><<<dim3(GD / 128, 1024 / 128), 256, 0, stream>>>(
      x, (const unsigned short*)(W + WI_T) + (size_t)d * GD * HD,
      (void*)((float*)(W + XP_O) + (size_t)d * 1024 * GD),
      bias, nullptr, 1024, GD, HD, d);
  }

  // Phase 4: fused two-layer scan (513 rounds)
  lstm_scan2<<<256, 768, 0, stream>>>(
    (const _Float16*)(W + WF_T),                          // Wf layer0 [2dir]
    (const _Float16*)(W + WF_T) + (size_t)2 * GD * HD,    // Wf layer1 [2dir]
    (const _Float16*)(W + WG_T),                          // Wg [2dir]
    (const float*)(W + XP_O),
    b_f + GD, b_b + GD,                                   // layer-1 biases
    (unsigned short*)(W + P_O),
    (unsigned short*)(W + P1_O),
    (unsigned int*)(W + PB_O),
    (unsigned int*)(W + CTR_O));

  // Phase 5: projections -> Hcat (layer0 plain, layer1 + residual)
  for (int d = 0; d < 2; d++) {
    gemm_k<0, 2><<<dim3(HD / 128, 1024 / 128), 256, 0, stream>>>(
      (const unsigned short*)(W + P_O) + (size_t)d * 1024 * HD,
      (const unsigned short*)(W + WP_T) + (size_t)d * HD * HD,
      (void*)((unsigned short*)(W + HCAT) + (size_t)(d * 2048) * HD),
      nullptr, nullptr, 1024, HD, HD, d);
  }
  for (int d = 0; d < 2; d++) {
    gemm_k<0, 2><<<dim3(HD / 128, 1024 / 128), 256, 0, stream>>>(
      (const unsigned short*)(W + P1_O) + (size_t)d * 1024 * HD,
      (const unsigned short*)(W + WP_T) + (size_t)(2 + d) * HD * HD,
      (void*)((unsigned short*)(W + HCAT) + (size_t)(d * 2048 + 1024) * HD),
      nullptr,
      (const unsigned short*)(W + HCAT) + (size_t)(d * 2048) * HD,
      1024, HD, HD, d);
  }

  // Phase 6: W_lin^T (WI_T/WP_T regions dead now)
  transpose_cvt<<<dim3(VOC / 32, HD / 32), 256, 0, stream>>>(
    Wlin, (unsigned short*)(W + WLIN_T), HD, VOC);

  // Phase 7: logits = Hcat @ W_lin + b_lin -> d_out
  gemm_k<0, 3><<<dim3(VOC / 128, 4096 / 128), 256, 0, stream>>>(
    (const unsigned short*)(W + HCAT), (const unsigned short*)(W + WLIN_T),
    d_out, blin, nullptr, 4096, VOC, HD, 0);
}